// Round 8
// baseline (6006.829 us; speedup 1.0000x reference)
//
#include <hip/hip_runtime.h>

typedef __attribute__((ext_vector_type(8))) short short8;
typedef __attribute__((ext_vector_type(4))) float floatx4;

#define DIN  512
#define HSZ  1024
#define G4   4096
#define KTOT 1536
#define BQ   256
#define TT   256

#define MFMA __builtin_amdgcn_mfma_f32_16x16x32_bf16

__device__ __forceinline__ unsigned short f2bf(float f){
  unsigned int u = __float_as_uint(f);
  u += 0x7fffu + ((u >> 16) & 1u);
  return (unsigned short)(u >> 16);
}
__device__ __forceinline__ unsigned int pack2(float a, float b){
  return (unsigned int)f2bf(a) | ((unsigned int)f2bf(b) << 16);
}

// ---------------- prep kernels ----------------
__global__ void prep_wcat(const float* __restrict__ wx, const float* __restrict__ wh,
                          const float* __restrict__ bx, const float* __restrict__ bh,
                          unsigned short* __restrict__ Wcat, float* __restrict__ bias){
  int gid = blockIdx.x * blockDim.x + threadIdx.x;
  int idx = gid * 8;
  int g = idx / KTOT;
  int k = idx - g * KTOT;
  const float* src = (k < DIN) ? (wx + (size_t)g * DIN + k)
                               : (wh + (size_t)g * HSZ + (k - DIN));
  float4 f0 = *(const float4*)(src);
  float4 f1 = *(const float4*)(src + 4);
  uint4 v = make_uint4(pack2(f0.x,f0.y), pack2(f0.z,f0.w), pack2(f1.x,f1.y), pack2(f1.z,f1.w));
  *(uint4*)(Wcat + (size_t)g * KTOT + k) = v;
  if (gid < G4) bias[gid] = bx[gid] + bh[gid];
}

__global__ void prep_wfc(const float* __restrict__ wfc, unsigned short* __restrict__ Wfcb){
  int gid = blockIdx.x * blockDim.x + threadIdx.x;
  int idx = gid * 8;
  int n = idx >> 10;
  int k = idx & 1023;
  uint4 v;
  if (n < 1000){
    const float* src = wfc + (size_t)n * 1024 + k;
    float4 f0 = *(const float4*)(src);
    float4 f1 = *(const float4*)(src + 4);
    v = make_uint4(pack2(f0.x,f0.y), pack2(f0.z,f0.w), pack2(f1.x,f1.y), pack2(f1.z,f1.w));
  } else {
    v = make_uint4(0u, 0u, 0u, 0u);
  }
  *(uint4*)(Wfcb + idx) = v;
}

// x[b][t][d] fp32 -> xbf[t][b][d] bf16
__global__ void prep_x(const float* __restrict__ x, unsigned short* __restrict__ xbf){
  int gid = blockIdx.x * 256 + threadIdx.x;
  int d8 = gid & 63;
  int b  = (gid >> 6) & 255;
  int t  = gid >> 14;
  const float* src = x + (((size_t)b * TT) + t) * DIN + d8 * 8;
  float4 f0 = *(const float4*)(src);
  float4 f1 = *(const float4*)(src + 4);
  uint4 v = make_uint4(pack2(f0.x,f0.y), pack2(f0.z,f0.w), pack2(f1.x,f1.y), pack2(f1.z,f1.w));
  *(uint4*)(xbf + (((size_t)t * BQ) + b) * DIN + d8 * 8) = v;
}

__global__ void init_misc(unsigned int* __restrict__ h0w, unsigned int* __restrict__ flags, int nflags){
  int gid = blockIdx.x * 256 + threadIdx.x;
  if (gid < 131072) h0w[gid] = 0u;   // hseq[0]: 256*1024 bf16
  if (gid < nflags) flags[gid] = 0u;
}

// ---------------- persistent LSTM: two interleaved batch-chains ----------------
// 256 blocks x 512 threads. Block bx owns 4 hidden units (16 gate-cols) for BOTH
// chains (chain 0 = rows 0..127, chain 1 = rows 128..255). Per round t:
//   [x_A loads][poll A(t)][GEMM_A][elem_A][publish A]  then same for B.
// Chain A's sync slack = the whole B half-round (and vice versa) -> stragglers
// and flag propagation hide under useful work. W slice (16 cols x 1536 K) in
// 48 KB LDS; 8 waves = 4 row-groups x 2 K-groups; partials merge in Gt2.
__global__ __launch_bounds__(512, 2)
void lstm_persist(const unsigned short* __restrict__ xbf,
                  const unsigned short* __restrict__ Wcat,
                  const float* __restrict__ bias,
                  unsigned short* __restrict__ hseq,   // [257][256][1024] bf16
                  unsigned int* __restrict__ flags){   // [2][256] u32, monotonic
  extern __shared__ char smem[];
  char*  Ws  = smem;                      // 16 * 3072 = 49152
  float* Gt2 = (float*)(smem + 49152);    // 2 * 128 * 18 * 4 = 18432
  float* Bls = (float*)(smem + 67584);    // 16 floats

  const int tid  = threadIdx.x;
  const int bx   = blockIdx.x;
  const int u0   = bx << 2;          // 4 hidden units
  const int lane = tid & 63;
  const int w    = tid >> 6;
  const int kg   = w & 1;            // K half
  const int rg   = w >> 1;           // row group (32 rows)

  // ---- one-time: W slice -> LDS (XOR swizzled), bias -> LDS ----
  {
    int c   = tid >> 5;              // 0..15: col = gate*4 + unit
    int chn = tid & 31;              // 32 threads/col, 96 B each
    int grow = (c >> 2) * HSZ + u0 + (c & 3);
    const char* src = (const char*)(Wcat + (size_t)grow * KTOT);
    char* dst = Ws + c * 3072;
    int xr = (c & 7) << 4;
    #pragma unroll
    for (int q = 0; q < 6; ++q){
      int k2 = chn * 96 + q * 16;
      *(uint4*)(dst + (k2 ^ xr)) = *(const uint4*)(src + k2);
    }
    if (tid < 16) Bls[tid] = bias[(size_t)(tid >> 2) * HSZ + u0 + (tid & 3)];
  }
  __syncthreads();

  const int kq8 = (lane >> 4) * 8;
  const int cA  = lane & 15;         // B col (16 total)
  const char* bpA = Ws + cA * 3072;
  const int xorA = (cA & 7) << 4;

  // elementwise mapping: tid<256 -> row = tid>>1, unit pair = (tid&1)*2
  const int erow = tid >> 1;
  const int eup  = (tid & 1) * 2;

  float cA0 = 0.f, cA1 = 0.f;        // c-state chain 0
  float cB0 = 0.f, cB1 = 0.f;        // c-state chain 1

  auto step_chain = [&](int chain, int t, float& cs0, float& cs1){
    const unsigned short* hin  = hseq + (size_t)t * (BQ * HSZ);
    unsigned short*       hout = hseq + (size_t)(t + 1) * (BQ * HSZ);
    const size_t rowA0 = (size_t)(chain * 128 + rg * 32 + (lane & 15));

    // ---- x A-loads (latency hides under the poll) ----
    short8 X0[8], X1[8];
    {
      const unsigned short* xr0p = xbf + ((size_t)t * BQ + rowA0) * DIN + kg * 256 + kq8;
      const unsigned short* xr1p = xr0p + 16 * DIN;
      #pragma unroll
      for (int p = 0; p < 8; ++p){
        X0[p] = *(const short8*)(xr0p + p * 32);
        X1[p] = *(const short8*)(xr1p + p * 32);
      }
    }
    __builtin_amdgcn_sched_barrier(0);

    // ---- poll: all 256 producers of this chain at step >= t ----
    if (t > 0){
      if (tid < 64){
        const unsigned int* fz = flags + (chain << 8);
        while (true){
          unsigned int v0 = __hip_atomic_load(fz + lane,       __ATOMIC_RELAXED, __HIP_MEMORY_SCOPE_AGENT);
          unsigned int v1 = __hip_atomic_load(fz + 64  + lane, __ATOMIC_RELAXED, __HIP_MEMORY_SCOPE_AGENT);
          unsigned int v2 = __hip_atomic_load(fz + 128 + lane, __ATOMIC_RELAXED, __HIP_MEMORY_SCOPE_AGENT);
          unsigned int v3 = __hip_atomic_load(fz + 192 + lane, __ATOMIC_RELAXED, __HIP_MEMORY_SCOPE_AGENT);
          bool ok = (v0 >= (unsigned)t) && (v1 >= (unsigned)t) &&
                    (v2 >= (unsigned)t) && (v3 >= (unsigned)t);
          if (__ballot(ok) == ~0ull) break;
          __builtin_amdgcn_s_sleep(2);
        }
      }
      __syncthreads();
      asm volatile("" ::: "memory");
    }

    floatx4 acc[2][2];   // [bank][rf]
    #pragma unroll
    for (int ab = 0; ab < 2; ++ab)
      #pragma unroll
      for (int rf = 0; rf < 2; ++rf)
        acc[ab][rf] = (floatx4){0.f,0.f,0.f,0.f};

    // ---- x-part MFMAs (B from LDS, depth-2 rotation) ----
    {
      const int bbase = kg * 512 + kq8 * 2;
      short8 bA[2];
      bA[0] = *(const short8*)(bpA + ((bbase     ) ^ xorA));
      bA[1] = *(const short8*)(bpA + ((bbase + 64) ^ xorA));
      #pragma unroll
      for (int j = 0; j < 8; ++j){
        const int sl = j & 1;
        short8 b0v = bA[sl];
        if (j < 6) bA[sl] = *(const short8*)(bpA + ((bbase + (j + 2) * 64) ^ xorA));
        acc[sl][0] = MFMA(X0[j], b0v, acc[sl][0], 0, 0, 0);
        acc[sl][1] = MFMA(X1[j], b0v, acc[sl][1], 0, 0, 0);
      }
    }

    // ---- h-part: 32 A-loads batched, then MFMAs ----
    {
      const unsigned short* hr0 = hin + rowA0 * HSZ + kg * 512 + kq8;
      const unsigned short* hr1 = hr0 + 16 * HSZ;
      short8 HA0[16], HA1[16];
      #pragma unroll
      for (int p = 0; p < 16; ++p){
        HA0[p] = *(const short8*)(hr0 + p * 32);
        HA1[p] = *(const short8*)(hr1 + p * 32);
      }
      __builtin_amdgcn_sched_barrier(0);
      const int kb2 = 1024 + kg * 1024 + kq8 * 2;
      short8 bA[2];
      bA[0] = *(const short8*)(bpA + ((kb2     ) ^ xorA));
      bA[1] = *(const short8*)(bpA + ((kb2 + 64) ^ xorA));
      #pragma unroll
      for (int j = 0; j < 16; ++j){
        const int sl = j & 1;
        short8 b0v = bA[sl];
        if (j < 14) bA[sl] = *(const short8*)(bpA + ((kb2 + (j + 2) * 64) ^ xorA));
        acc[sl][0] = MFMA(HA0[j], b0v, acc[sl][0], 0, 0, 0);
        acc[sl][1] = MFMA(HA1[j], b0v, acc[sl][1], 0, 0, 0);
      }
    }

    // ---- partial gates -> Gt2[kg] ----
    {
      float* gd = Gt2 + kg * (128 * 18);
      int r0 = rg * 32 + (lane >> 4) * 4;
      #pragma unroll
      for (int rf = 0; rf < 2; ++rf){
        floatx4 g = acc[0][rf] + acc[1][rf];
        #pragma unroll
        for (int r = 0; r < 4; ++r)
          gd[(r0 + rf * 16 + r) * 18 + cA] = g[r];
      }
    }
    __syncthreads();

    // ---- elementwise: 1 row x 2 units per thread (tid<256) ----
    if (tid < 256){
      const float* g0p = Gt2 + erow * 18;
      const float* g1p = g0p + 128 * 18;
      float gi0 = g0p[     eup] + g1p[     eup] + Bls[     eup];
      float gf0 = g0p[ 4 + eup] + g1p[ 4 + eup] + Bls[ 4 + eup];
      float gg0 = g0p[ 8 + eup] + g1p[ 8 + eup] + Bls[ 8 + eup];
      float go0 = g0p[12 + eup] + g1p[12 + eup] + Bls[12 + eup];
      float gi1 = g0p[     eup + 1] + g1p[     eup + 1] + Bls[     eup + 1];
      float gf1 = g0p[ 4 + eup + 1] + g1p[ 4 + eup + 1] + Bls[ 4 + eup + 1];
      float gg1 = g0p[ 8 + eup + 1] + g1p[ 8 + eup + 1] + Bls[ 8 + eup + 1];
      float go1 = g0p[12 + eup + 1] + g1p[12 + eup + 1] + Bls[12 + eup + 1];

      float iv0 = 1.f / (1.f + __expf(-gi0));
      float fv0 = 1.f / (1.f + __expf(-gf0));
      float e20 = __expf(-2.f * fmaxf(fminf(gg0, 30.f), -30.f));
      float gv0 = (1.f - e20) / (1.f + e20);
      float ov0 = 1.f / (1.f + __expf(-go0));
      float cn0 = cs0 * fv0 + iv0 * gv0;
      cs0 = cn0;
      float ec0 = __expf(-2.f * fmaxf(fminf(cn0, 30.f), -30.f));
      float hv0 = ov0 * (1.f - ec0) / (1.f + ec0);

      float iv1 = 1.f / (1.f + __expf(-gi1));
      float fv1 = 1.f / (1.f + __expf(-gf1));
      float e21 = __expf(-2.f * fmaxf(fminf(gg1, 30.f), -30.f));
      float gv1 = (1.f - e21) / (1.f + e21);
      float ov1 = 1.f / (1.f + __expf(-go1));
      float cn1 = cs1 * fv1 + iv1 * gv1;
      cs1 = cn1;
      float ec1 = __expf(-2.f * fmaxf(fminf(cn1, 30.f), -30.f));
      float hv1 = ov1 * (1.f - ec1) / (1.f + ec1);

      __hip_atomic_store((unsigned int*)(hout + (size_t)(chain * 128 + erow) * HSZ + u0 + eup),
                         pack2(hv0, hv1), __ATOMIC_RELAXED, __HIP_MEMORY_SCOPE_AGENT);
    }
    __syncthreads();  // drains h-stores (vmcnt 0) in every wave before the flag

    // ---- arrive: monotonic flag = published step (RMW-free) ----
    if (tid == 0)
      __hip_atomic_store(&flags[(chain << 8) + bx], (unsigned)(t + 1),
                         __ATOMIC_RELAXED, __HIP_MEMORY_SCOPE_AGENT);
  };

  for (int t = 0; t < TT; ++t){
    step_chain(0, t, cA0, cA1);
    step_chain(1, t, cB0, cB1);
  }
}

// ---------------- final FC: out[256][1000] = h @ Wfc^T + b ----------------
__global__ __launch_bounds__(256, 1)
void fc_kernel(const unsigned short* __restrict__ h, const unsigned short* __restrict__ wfc,
               const float* __restrict__ bfc, float* __restrict__ out){
  int bx = blockIdx.x, tid = threadIdx.x;
  int wave = tid >> 6, lane = tid & 63;
  int row0 = (bx >> 4) * 64 + wave * 16;
  int col0 = (bx & 15) * 64;
  int lr = lane & 15, lk = (lane >> 4) * 8;
  floatx4 acc[4] = {{0.f,0.f,0.f,0.f},{0.f,0.f,0.f,0.f},{0.f,0.f,0.f,0.f},{0.f,0.f,0.f,0.f}};
  #pragma unroll 4
  for (int ks = 0; ks < 32; ++ks){
    int k = ks * 32 + lk;
    short8 a = *(const short8*)(h + (size_t)(row0 + lr) * 1024 + k);
    #pragma unroll
    for (int fj = 0; fj < 4; ++fj){
      short8 b = *(const short8*)(wfc + (size_t)(col0 + fj * 16 + lr) * 1024 + k);
      acc[fj] = MFMA(a, b, acc[fj], 0, 0, 0);
    }
  }
  #pragma unroll
  for (int fj = 0; fj < 4; ++fj){
    int col = col0 + fj * 16 + lr;
    if (col < 1000){
      #pragma unroll
      for (int r = 0; r < 4; ++r){
        int row = row0 + (lane >> 4) * 4 + r;
        out[(size_t)row * 1000 + col] = acc[fj][r] + bfc[col];
      }
    }
  }
}

// ---------------- launch ----------------
extern "C" void kernel_launch(void* const* d_in, const int* in_sizes, int n_in,
                              void* d_out, int out_size, void* d_ws, size_t ws_size,
                              hipStream_t stream){
  const float* x    = (const float*)d_in[0];
  const float* wx2h = (const float*)d_in[1];
  const float* bx2h = (const float*)d_in[2];
  const float* wh2h = (const float*)d_in[3];
  const float* bh2h = (const float*)d_in[4];
  const float* wfc  = (const float*)d_in[5];
  const float* bfc  = (const float*)d_in[6];
  float* out = (float*)d_out;
  char* ws = (char*)d_ws;

  // ws layout (bytes)
  unsigned short* Wcat  = (unsigned short*)(ws + 0);             //  12,582,912
  unsigned short* Wfcb  = (unsigned short*)(ws + 12582912);      //   2,097,152
  float*          bias  = (float*)         (ws + 14680064);      //      16,384
  unsigned short* xbf   = (unsigned short*)(ws + 14696448);      //  67,108,864
  unsigned short* hseq  = (unsigned short*)(ws + 81805312);      // 134,742,016 (257 x 512KB)
  unsigned int*   flags = (unsigned int*)  (ws + 216547328);     //       2,048 (2x256 u32)
  // total ~216.5 MB

  (void)hipFuncSetAttribute((const void*)lstm_persist,
                            hipFuncAttributeMaxDynamicSharedMemorySize, 67712);

  hipLaunchKernelGGL(prep_wcat, dim3(3072), dim3(256), 0, stream, wx2h, wh2h, bx2h, bh2h, Wcat, bias);
  hipLaunchKernelGGL(prep_wfc,  dim3(512),  dim3(256), 0, stream, wfc, Wfcb);
  hipLaunchKernelGGL(prep_x,    dim3(16384),dim3(256), 0, stream, x, xbf);
  hipLaunchKernelGGL(init_misc, dim3(512),  dim3(256), 0, stream,
                     (unsigned int*)hseq, flags, 512);

  hipLaunchKernelGGL(lstm_persist, dim3(256), dim3(512), 67712, stream,
                     xbf, Wcat, bias, hseq, flags);

  // final h = hseq[256]
  hipLaunchKernelGGL(fc_kernel, dim3(64), dim3(256), 0, stream,
                     hseq + (size_t)256 * BQ * HSZ, Wfcb, bfc, out);
}

// Round 9
// 4539.740 us; speedup vs baseline: 1.3232x; 1.3232x over previous
//
#include <hip/hip_runtime.h>

typedef __attribute__((ext_vector_type(8))) short short8;
typedef __attribute__((ext_vector_type(4))) float floatx4;

#define DIN  512
#define HSZ  1024
#define G4   4096
#define KTOT 1536
#define BQ   256
#define TT   256

#define MFMA __builtin_amdgcn_mfma_f32_16x16x32_bf16

__device__ __forceinline__ unsigned short f2bf(float f){
  unsigned int u = __float_as_uint(f);
  u += 0x7fffu + ((u >> 16) & 1u);
  return (unsigned short)(u >> 16);
}
__device__ __forceinline__ unsigned int pack2(float a, float b){
  return (unsigned int)f2bf(a) | ((unsigned int)f2bf(b) << 16);
}

// ---------------- prep kernels ----------------
__global__ void prep_wcat(const float* __restrict__ wx, const float* __restrict__ wh,
                          const float* __restrict__ bx, const float* __restrict__ bh,
                          unsigned short* __restrict__ Wcat, float* __restrict__ bias){
  int gid = blockIdx.x * blockDim.x + threadIdx.x;
  int idx = gid * 8;
  int g = idx / KTOT;
  int k = idx - g * KTOT;
  const float* src = (k < DIN) ? (wx + (size_t)g * DIN + k)
                               : (wh + (size_t)g * HSZ + (k - DIN));
  float4 f0 = *(const float4*)(src);
  float4 f1 = *(const float4*)(src + 4);
  uint4 v = make_uint4(pack2(f0.x,f0.y), pack2(f0.z,f0.w), pack2(f1.x,f1.y), pack2(f1.z,f1.w));
  *(uint4*)(Wcat + (size_t)g * KTOT + k) = v;
  if (gid < G4) bias[gid] = bx[gid] + bh[gid];
}

__global__ void prep_wfc(const float* __restrict__ wfc, unsigned short* __restrict__ Wfcb){
  int gid = blockIdx.x * blockDim.x + threadIdx.x;
  int idx = gid * 8;
  int n = idx >> 10;
  int k = idx & 1023;
  uint4 v;
  if (n < 1000){
    const float* src = wfc + (size_t)n * 1024 + k;
    float4 f0 = *(const float4*)(src);
    float4 f1 = *(const float4*)(src + 4);
    v = make_uint4(pack2(f0.x,f0.y), pack2(f0.z,f0.w), pack2(f1.x,f1.y), pack2(f1.z,f1.w));
  } else {
    v = make_uint4(0u, 0u, 0u, 0u);
  }
  *(uint4*)(Wfcb + idx) = v;
}

// x[b][t][d] fp32 -> xbf[t][b][d] bf16
__global__ void prep_x(const float* __restrict__ x, unsigned short* __restrict__ xbf){
  int gid = blockIdx.x * 256 + threadIdx.x;
  int d8 = gid & 63;
  int b  = (gid >> 6) & 255;
  int t  = gid >> 14;
  const float* src = x + (((size_t)b * TT) + t) * DIN + d8 * 8;
  float4 f0 = *(const float4*)(src);
  float4 f1 = *(const float4*)(src + 4);
  uint4 v = make_uint4(pack2(f0.x,f0.y), pack2(f0.z,f0.w), pack2(f1.x,f1.y), pack2(f1.z,f1.w));
  *(uint4*)(xbf + (((size_t)t * BQ) + b) * DIN + d8 * 8) = v;
}

// zero h0 (131072 u32) and c (262144 u32)
__global__ void init_misc(unsigned int* __restrict__ h0w, unsigned int* __restrict__ cw){
  int gid = blockIdx.x * 256 + threadIdx.x;
  if (gid < 131072) h0w[gid] = 0u;
  cw[gid] = 0u;
}

// ---------------- per-step LSTM kernel (dispatch boundary = barrier) ----------------
// grid 256 x 512 thr. bg = bx>>7 (128-row half), hb = bx&127 (8 units, 32 gate-cols).
// 8 waves = 4 row-groups x 2 K-groups. W slice staged to LDS each dispatch (96 KB,
// L2-warm). Plain loads/stores only; c-state in global ws.
__global__ __launch_bounds__(512, 2)
void lstm_step(const unsigned short* __restrict__ xt,    // xbf + t*BQ*DIN
               const unsigned short* __restrict__ Wcat,
               const float* __restrict__ bias,
               const unsigned short* __restrict__ hin,
               unsigned short* __restrict__ hout,
               float* __restrict__ cstg){
  extern __shared__ char smem[];
  char*  Ws  = smem;                            // 32 * 3072 = 98304
  float* Gt2 = (float*)(smem + 98304);          // 2 * 128 * 34 * 4 = 34816
  float* Bls = (float*)(smem + 98304 + 34816);  // 32 floats

  const int tid  = threadIdx.x;
  const int bx   = blockIdx.x;
  const int bg   = bx >> 7;
  const int b0   = bg << 7;
  const int hb   = bx & 127;
  const int u0   = hb << 3;
  const int lane = tid & 63;
  const int w    = tid >> 6;
  const int kg   = w & 1;            // K half
  const int rg   = w >> 1;           // row group (32 rows)

  const int kq8 = (lane >> 4) * 8;
  const size_t rowA0 = (size_t)(b0 + rg * 32 + (lane & 15));

  // ---- x A-loads issued first: latency hides under the W-stage ----
  short8 X0[8], X1[8];
  {
    const unsigned short* xr0p = xt + rowA0 * DIN + kg * 256 + kq8;
    const unsigned short* xr1p = xr0p + 16 * DIN;
    #pragma unroll
    for (int p = 0; p < 8; ++p){
      X0[p] = *(const short8*)(xr0p + p * 32);
      X1[p] = *(const short8*)(xr1p + p * 32);
    }
  }
  __builtin_amdgcn_sched_barrier(0);

  // ---- W slice -> LDS (XOR swizzled), bias -> LDS ----
  {
    int c  = tid >> 4;               // 0..31: col = gate*8 + unit
    int ch = tid & 15;               // 16 threads/col, 192 B each
    int grow = (c >> 3) * HSZ + u0 + (c & 7);
    const char* src = (const char*)(Wcat + (size_t)grow * KTOT);
    char* dst = Ws + c * 3072;
    int xr = (c & 7) << 4;
    #pragma unroll
    for (int q = 0; q < 12; ++q){
      int k2 = ch * 192 + q * 16;
      *(uint4*)(dst + (k2 ^ xr)) = *(const uint4*)(src + k2);
    }
    if (tid < 32) Bls[tid] = bias[(size_t)(tid >> 3) * HSZ + u0 + (tid & 7)];
  }
  __syncthreads();

  const int cA  = lane & 15;
  const int cB  = 16 + (lane & 15);
  const char* bpA = Ws + cA * 3072; const int xorA = (cA & 7) << 4;
  const char* bpB = Ws + cB * 3072; const int xorB = (cB & 7) << 4;

  floatx4 acc[2][2][2];   // [bank][rf][cf]
  #pragma unroll
  for (int ab = 0; ab < 2; ++ab)
    #pragma unroll
    for (int rf = 0; rf < 2; ++rf)
      #pragma unroll
      for (int cf = 0; cf < 2; ++cf)
        acc[ab][rf][cf] = (floatx4){0.f,0.f,0.f,0.f};

  // ---- x-part MFMAs (B from LDS, depth-2 rotation) ----
  {
    const int bbase = kg * 512 + kq8 * 2;
    short8 bA[2], bB[2];
    bA[0] = *(const short8*)(bpA + ((bbase     ) ^ xorA));
    bB[0] = *(const short8*)(bpB + ((bbase     ) ^ xorB));
    bA[1] = *(const short8*)(bpA + ((bbase + 64) ^ xorA));
    bB[1] = *(const short8*)(bpB + ((bbase + 64) ^ xorB));
    #pragma unroll
    for (int j = 0; j < 8; ++j){
      const int sl = j & 1;
      short8 b0v = bA[sl], b1v = bB[sl];
      if (j < 6){
        int bb = bbase + (j + 2) * 64;
        bA[sl] = *(const short8*)(bpA + (bb ^ xorA));
        bB[sl] = *(const short8*)(bpB + (bb ^ xorB));
      }
      acc[sl][0][0] = MFMA(X0[j], b0v, acc[sl][0][0], 0, 0, 0);
      acc[sl][0][1] = MFMA(X0[j], b1v, acc[sl][0][1], 0, 0, 0);
      acc[sl][1][0] = MFMA(X1[j], b0v, acc[sl][1][0], 0, 0, 0);
      acc[sl][1][1] = MFMA(X1[j], b1v, acc[sl][1][1], 0, 0, 0);
    }
  }

  // ---- h-part: 32 A-loads batched (plain), then MFMAs ----
  {
    const unsigned short* hr0 = hin + rowA0 * HSZ + kg * 512 + kq8;
    const unsigned short* hr1 = hr0 + 16 * HSZ;
    short8 HA0[16], HA1[16];
    #pragma unroll
    for (int p = 0; p < 16; ++p){
      HA0[p] = *(const short8*)(hr0 + p * 32);
      HA1[p] = *(const short8*)(hr1 + p * 32);
    }
    __builtin_amdgcn_sched_barrier(0);
    const int kb2 = 1024 + kg * 1024 + kq8 * 2;
    short8 bA[2], bB[2];
    bA[0] = *(const short8*)(bpA + ((kb2     ) ^ xorA));
    bB[0] = *(const short8*)(bpB + ((kb2     ) ^ xorB));
    bA[1] = *(const short8*)(bpA + ((kb2 + 64) ^ xorA));
    bB[1] = *(const short8*)(bpB + ((kb2 + 64) ^ xorB));
    #pragma unroll
    for (int j = 0; j < 16; ++j){
      const int sl = j & 1;
      short8 b0v = bA[sl], b1v = bB[sl];
      if (j < 14){
        int bb = kb2 + (j + 2) * 64;
        bA[sl] = *(const short8*)(bpA + (bb ^ xorA));
        bB[sl] = *(const short8*)(bpB + (bb ^ xorB));
      }
      acc[sl][0][0] = MFMA(HA0[j], b0v, acc[sl][0][0], 0, 0, 0);
      acc[sl][0][1] = MFMA(HA0[j], b1v, acc[sl][0][1], 0, 0, 0);
      acc[sl][1][0] = MFMA(HA1[j], b0v, acc[sl][1][0], 0, 0, 0);
      acc[sl][1][1] = MFMA(HA1[j], b1v, acc[sl][1][1], 0, 0, 0);
    }
  }

  // ---- partial gates -> Gt2[kg] ----
  {
    float* gdst = Gt2 + kg * (128 * 34);
    int r0 = rg * 32 + (lane >> 4) * 4;
    #pragma unroll
    for (int rf = 0; rf < 2; ++rf){
      floatx4 g0 = acc[0][rf][0] + acc[1][rf][0];
      floatx4 g1 = acc[0][rf][1] + acc[1][rf][1];
      #pragma unroll
      for (int r = 0; r < 4; ++r){
        gdst[(r0 + rf * 16 + r) * 34 + cA] = g0[r];
        gdst[(r0 + rf * 16 + r) * 34 + cB] = g1[r];
      }
    }
  }
  __syncthreads();

  // ---- elementwise: sum kg partials; c in global ws; plain h store ----
  {
    const int er = tid >> 2;           // 0..127
    const int up = (tid & 3) * 2;      // units up, up+1
    const float* g0p = Gt2 + er * 34;
    const float* g1p = g0p + 128 * 34;
    float gi0 = g0p[     up] + g1p[     up] + Bls[     up];
    float gf0 = g0p[ 8 + up] + g1p[ 8 + up] + Bls[ 8 + up];
    float gg0 = g0p[16 + up] + g1p[16 + up] + Bls[16 + up];
    float go0 = g0p[24 + up] + g1p[24 + up] + Bls[24 + up];
    float gi1 = g0p[     up + 1] + g1p[     up + 1] + Bls[     up + 1];
    float gf1 = g0p[ 8 + up + 1] + g1p[ 8 + up + 1] + Bls[ 8 + up + 1];
    float gg1 = g0p[16 + up + 1] + g1p[16 + up + 1] + Bls[16 + up + 1];
    float go1 = g0p[24 + up + 1] + g1p[24 + up + 1] + Bls[24 + up + 1];

    float2* cp = (float2*)(cstg + (size_t)(b0 + er) * HSZ + u0 + up);
    float2 cv = *cp;

    float iv0 = 1.f / (1.f + __expf(-gi0));
    float fv0 = 1.f / (1.f + __expf(-gf0));
    float e20 = __expf(-2.f * fmaxf(fminf(gg0, 30.f), -30.f));
    float gv0 = (1.f - e20) / (1.f + e20);
    float ov0 = 1.f / (1.f + __expf(-go0));
    float cn0 = cv.x * fv0 + iv0 * gv0;
    float ec0 = __expf(-2.f * fmaxf(fminf(cn0, 30.f), -30.f));
    float hv0 = ov0 * (1.f - ec0) / (1.f + ec0);

    float iv1 = 1.f / (1.f + __expf(-gi1));
    float fv1 = 1.f / (1.f + __expf(-gf1));
    float e21 = __expf(-2.f * fmaxf(fminf(gg1, 30.f), -30.f));
    float gv1 = (1.f - e21) / (1.f + e21);
    float ov1 = 1.f / (1.f + __expf(-go1));
    float cn1 = cv.y * fv1 + iv1 * gv1;
    float ec1 = __expf(-2.f * fmaxf(fminf(cn1, 30.f), -30.f));
    float hv1 = ov1 * (1.f - ec1) / (1.f + ec1);

    *cp = make_float2(cn0, cn1);
    *(unsigned int*)(hout + (size_t)(b0 + er) * HSZ + u0 + up) = pack2(hv0, hv1);
  }
}

// ---------------- final FC: out[256][1000] = h @ Wfc^T + b ----------------
__global__ __launch_bounds__(256, 1)
void fc_kernel(const unsigned short* __restrict__ h, const unsigned short* __restrict__ wfc,
               const float* __restrict__ bfc, float* __restrict__ out){
  int bx = blockIdx.x, tid = threadIdx.x;
  int wave = tid >> 6, lane = tid & 63;
  int row0 = (bx >> 4) * 64 + wave * 16;
  int col0 = (bx & 15) * 64;
  int lr = lane & 15, lk = (lane >> 4) * 8;
  floatx4 acc[4] = {{0.f,0.f,0.f,0.f},{0.f,0.f,0.f,0.f},{0.f,0.f,0.f,0.f},{0.f,0.f,0.f,0.f}};
  #pragma unroll 4
  for (int ks = 0; ks < 32; ++ks){
    int k = ks * 32 + lk;
    short8 a = *(const short8*)(h + (size_t)(row0 + lr) * 1024 + k);
    #pragma unroll
    for (int fj = 0; fj < 4; ++fj){
      short8 b = *(const short8*)(wfc + (size_t)(col0 + fj * 16 + lr) * 1024 + k);
      acc[fj] = MFMA(a, b, acc[fj], 0, 0, 0);
    }
  }
  #pragma unroll
  for (int fj = 0; fj < 4; ++fj){
    int col = col0 + fj * 16 + lr;
    if (col < 1000){
      #pragma unroll
      for (int r = 0; r < 4; ++r){
        int row = row0 + (lane >> 4) * 4 + r;
        out[(size_t)row * 1000 + col] = acc[fj][r] + bfc[col];
      }
    }
  }
}

// ---------------- launch ----------------
extern "C" void kernel_launch(void* const* d_in, const int* in_sizes, int n_in,
                              void* d_out, int out_size, void* d_ws, size_t ws_size,
                              hipStream_t stream){
  const float* x    = (const float*)d_in[0];
  const float* wx2h = (const float*)d_in[1];
  const float* bx2h = (const float*)d_in[2];
  const float* wh2h = (const float*)d_in[3];
  const float* bh2h = (const float*)d_in[4];
  const float* wfc  = (const float*)d_in[5];
  const float* bfc  = (const float*)d_in[6];
  float* out = (float*)d_out;
  char* ws = (char*)d_ws;

  // ws layout (bytes)
  unsigned short* Wcat = (unsigned short*)(ws + 0);            //  12,582,912
  unsigned short* Wfcb = (unsigned short*)(ws + 12582912);     //   2,097,152
  float*          bias = (float*)         (ws + 14680064);     //      16,384
  unsigned short* xbf  = (unsigned short*)(ws + 14696448);     //  67,108,864
  unsigned short* h0   = (unsigned short*)(ws + 81805312);     //     524,288
  unsigned short* h1   = (unsigned short*)(ws + 82329600);     //     524,288
  float*          cstg = (float*)         (ws + 82853888);     //   1,048,576
  // total ~83.9 MB

  (void)hipFuncSetAttribute((const void*)lstm_step,
                            hipFuncAttributeMaxDynamicSharedMemorySize, 133376);

  hipLaunchKernelGGL(prep_wcat, dim3(3072), dim3(256), 0, stream, wx2h, wh2h, bx2h, bh2h, Wcat, bias);
  hipLaunchKernelGGL(prep_wfc,  dim3(512),  dim3(256), 0, stream, wfc, Wfcb);
  hipLaunchKernelGGL(prep_x,    dim3(16384),dim3(256), 0, stream, x, xbf);
  hipLaunchKernelGGL(init_misc, dim3(1024), dim3(256), 0, stream,
                     (unsigned int*)h0, (unsigned int*)cstg);

  for (int t = 0; t < TT; ++t){
    const unsigned short* hin = (t & 1) ? h1 : h0;
    unsigned short*      hout = (t & 1) ? h0 : h1;
    hipLaunchKernelGGL(lstm_step, dim3(256), dim3(512), 133376, stream,
                       xbf + (size_t)t * BQ * DIN, Wcat, bias, hin, hout, cstg);
  }
  // t=255 (odd) wrote h0
  hipLaunchKernelGGL(fc_kernel, dim3(64), dim3(256), 0, stream, h0, Wfcb, bfc, out);
}

// Round 10
// 3546.829 us; speedup vs baseline: 1.6936x; 1.2799x over previous
//
#include <hip/hip_runtime.h>

typedef __attribute__((ext_vector_type(8))) short short8;
typedef __attribute__((ext_vector_type(4))) float floatx4;

#define DIN  512
#define HSZ  1024
#define G4   4096
#define KTOT 1536
#define BQ   256
#define TT   256

#define MFMA __builtin_amdgcn_mfma_f32_16x16x32_bf16

__device__ __forceinline__ unsigned short f2bf(float f){
  unsigned int u = __float_as_uint(f);
  u += 0x7fffu + ((u >> 16) & 1u);
  return (unsigned short)(u >> 16);
}
__device__ __forceinline__ unsigned int pack2(float a, float b){
  return (unsigned int)f2bf(a) | ((unsigned int)f2bf(b) << 16);
}

// ---------------- prep kernels ----------------
__global__ void prep_wcat(const float* __restrict__ wx, const float* __restrict__ wh,
                          const float* __restrict__ bx, const float* __restrict__ bh,
                          unsigned short* __restrict__ Wcat, float* __restrict__ bias){
  int gid = blockIdx.x * blockDim.x + threadIdx.x;
  int idx = gid * 8;
  int g = idx / KTOT;
  int k = idx - g * KTOT;
  const float* src = (k < DIN) ? (wx + (size_t)g * DIN + k)
                               : (wh + (size_t)g * HSZ + (k - DIN));
  float4 f0 = *(const float4*)(src);
  float4 f1 = *(const float4*)(src + 4);
  uint4 v = make_uint4(pack2(f0.x,f0.y), pack2(f0.z,f0.w), pack2(f1.x,f1.y), pack2(f1.z,f1.w));
  *(uint4*)(Wcat + (size_t)g * KTOT + k) = v;
  if (gid < G4) bias[gid] = bx[gid] + bh[gid];
}

__global__ void prep_wfc(const float* __restrict__ wfc, unsigned short* __restrict__ Wfcb){
  int gid = blockIdx.x * blockDim.x + threadIdx.x;
  int idx = gid * 8;
  int n = idx >> 10;
  int k = idx & 1023;
  uint4 v;
  if (n < 1000){
    const float* src = wfc + (size_t)n * 1024 + k;
    float4 f0 = *(const float4*)(src);
    float4 f1 = *(const float4*)(src + 4);
    v = make_uint4(pack2(f0.x,f0.y), pack2(f0.z,f0.w), pack2(f1.x,f1.y), pack2(f1.z,f1.w));
  } else {
    v = make_uint4(0u, 0u, 0u, 0u);
  }
  *(uint4*)(Wfcb + idx) = v;
}

// x[b][t][d] fp32 -> xbf[t][b][d] bf16
__global__ void prep_x(const float* __restrict__ x, unsigned short* __restrict__ xbf){
  int gid = blockIdx.x * 256 + threadIdx.x;
  int d8 = gid & 63;
  int b  = (gid >> 6) & 255;
  int t  = gid >> 14;
  const float* src = x + (((size_t)b * TT) + t) * DIN + d8 * 8;
  float4 f0 = *(const float4*)(src);
  float4 f1 = *(const float4*)(src + 4);
  uint4 v = make_uint4(pack2(f0.x,f0.y), pack2(f0.z,f0.w), pack2(f1.x,f1.y), pack2(f1.z,f1.w));
  *(uint4*)(xbf + (((size_t)t * BQ) + b) * DIN + d8 * 8) = v;
}

__global__ void init_misc(unsigned int* __restrict__ h0w, unsigned int* __restrict__ flags, int nflags){
  int gid = blockIdx.x * 256 + threadIdx.x;
  if (gid < 131072) h0w[gid] = 0u;   // hseq[0]
  if (gid < nflags) flags[gid] = 0u;
}

// ---------------- persistent LSTM, K-split pairs ----------------
// 256 blocks x 512 threads. bx = bg*128 + cg*2 + kg.
//   bg: 128-row batch half; cg: 16 hidden units (64 gate-cols); kg: K half (768).
// W slice 64 cols x 768 K in LDS (96 KB). A-traffic per block = 128x768x2B = 192 KB
// (half of round 5). kg pair (bx ^ 1) exchanges f32 partial gates (row-halved,
// 16 KB each way, double-buffered by t&1); each side does elem for its row half.
// Waves: 4 rg (32 rows) x 2 kgg (384 K). Gates merge two-pass in Gt.
__global__ __launch_bounds__(512, 2)
void lstm_persist(const unsigned short* __restrict__ xbf,
                  const unsigned short* __restrict__ Wcat,
                  const float* __restrict__ bias,
                  unsigned short* __restrict__ hseq,   // [257][256][1024] bf16
                  float* __restrict__ pbuf,            // [2][256][4096] f32
                  unsigned int* __restrict__ hflags,   // [256] monotonic
                  unsigned int* __restrict__ pflags){  // [256] monotonic
  extern __shared__ char smem[];
  char*  Ws  = smem;                            // 64 * 1536 = 98304
  float* Gt  = (float*)(smem + 98304);          // 128 * 68 * 4 = 34816
  float* Bls = (float*)(smem + 98304 + 34816);  // 64 floats

  const int tid  = threadIdx.x;
  const int bx   = blockIdx.x;
  const int bg   = bx >> 7;
  const int cg   = (bx & 127) >> 1;
  const int kg   = bx & 1;
  const int b0   = bg << 7;
  const int u0   = cg << 4;          // 16 units
  const int lane = tid & 63;
  const int w    = tid >> 6;
  const int rg   = w >> 1;           // 0..3 (32 rows)
  const int kgg  = w & 1;            // K sub-half (384)

  // ---- one-time: W slice -> LDS (XOR swizzled), bias -> LDS ----
  {
    int c  = tid >> 3;               // 0..63: col = gate*16 + unit
    int ch = tid & 7;                // 8 chunks x 192 B = 1536 B/col
    int grow = (c >> 4) * HSZ + u0 + (c & 15);
    const char* src = (const char*)(Wcat + (size_t)grow * KTOT + kg * 768);
    char* dst = Ws + c * 1536;
    int xr = (c & 7) << 4;
    #pragma unroll
    for (int q = 0; q < 12; ++q){
      int k2 = ch * 192 + q * 16;
      *(uint4*)(dst + (k2 ^ xr)) = *(const uint4*)(src + k2);
    }
    if (tid < 64) Bls[tid] = bias[(size_t)(tid >> 4) * HSZ + u0 + (tid & 15)];
  }
  __syncthreads();

  const int kq8 = (lane >> 4) * 8;
  const int cb  = lane & 15;
  const char* bp[4]; int xr4[4];
  #pragma unroll
  for (int cf = 0; cf < 4; ++cf){
    int c = cf * 16 + cb;
    bp[cf]  = Ws + c * 1536;
    xr4[cf] = (c & 7) << 4;
  }

  const int kstart = kg * 768 + kgg * 384;          // global K base for this wave
  const int nx = (kstart < 512) ? (((512 - kstart) + 31) >> 5) : 0;  // #x-ks (<=12)
  const size_t rowA = (size_t)(b0 + rg * 32 + (lane & 15));

  // elementwise mapping (fixed; c-state in regs); rows kg*64 + (tid>>3)
  const int erl = kg * 64 + (tid >> 3);
  const int eup = (tid & 7) * 2;
  float cst0 = 0.f, cst1 = 0.f;

  for (int t = 0; t < TT; ++t){
    const unsigned short* hin  = hseq + (size_t)t * (BQ * HSZ);
    unsigned short*       hout = hseq + (size_t)(t + 1) * (BQ * HSZ);

    // ===== x A-loads (pre-wait; latency hides under poll) =====
    short8 A0[12], A1[12];
    {
      const unsigned short* xr0 = xbf + ((size_t)t * BQ + rowA) * DIN + kq8;
      const unsigned short* xr1 = xr0 + 16 * DIN;
      #pragma unroll
      for (int p = 0; p < 12; ++p){
        if (p < nx){
          int kgl = kstart + p * 32;
          A0[p] = *(const short8*)(xr0 + kgl);
          A1[p] = *(const short8*)(xr1 + kgl);
        }
      }
    }
    __builtin_amdgcn_sched_barrier(0);

    // ===== wait: h[t] units in this block's K range =====
    if (t > 0){
      if (tid < 64){
        const unsigned int* base = hflags + (bg << 7);
        int i1 = (kg == 0) ? (lane & 31) : (32 + lane);
        int i2 = (kg == 0) ? (lane & 31) : (96 + (lane & 31));
        while (true){
          unsigned int v1 = __hip_atomic_load(base + i1, __ATOMIC_RELAXED, __HIP_MEMORY_SCOPE_AGENT);
          unsigned int v2 = __hip_atomic_load(base + i2, __ATOMIC_RELAXED, __HIP_MEMORY_SCOPE_AGENT);
          if (__ballot(v1 >= (unsigned)t && v2 >= (unsigned)t) == ~0ull) break;
          __builtin_amdgcn_s_sleep(1);
        }
      }
      __syncthreads();
      asm volatile("" ::: "memory");
    }

    // ===== h A-loads (post-wait, batched) =====
    {
      const unsigned short* hr0 = hin + rowA * HSZ + kq8;
      const unsigned short* hr1 = hr0 + 16 * HSZ;
      #pragma unroll
      for (int p = 0; p < 12; ++p){
        if (p >= nx){
          int hu = kstart + p * 32 - 512;   // h element index
          A0[p] = *(const short8*)(hr0 + hu);
          A1[p] = *(const short8*)(hr1 + hu);
        }
      }
    }
    __builtin_amdgcn_sched_barrier(0);

    // ===== MFMAs: 12 ks x (2 rf x 4 cf), B from LDS depth-2 =====
    floatx4 acc[2][4];
    #pragma unroll
    for (int rf = 0; rf < 2; ++rf)
      #pragma unroll
      for (int cf = 0; cf < 4; ++cf)
        acc[rf][cf] = (floatx4){0.f,0.f,0.f,0.f};
    {
      const int kOff = kgg * 768 + kq8 * 2;   // byte offset in 768-K slice
      short8 Bv[4][2];
      #pragma unroll
      for (int cf = 0; cf < 4; ++cf){
        Bv[cf][0] = *(const short8*)(bp[cf] + ((kOff     ) ^ xr4[cf]));
        Bv[cf][1] = *(const short8*)(bp[cf] + ((kOff + 64) ^ xr4[cf]));
      }
      #pragma unroll
      for (int p = 0; p < 12; ++p){
        const int sl = p & 1;
        short8 b0v = Bv[0][sl], b1v = Bv[1][sl], b2v = Bv[2][sl], b3v = Bv[3][sl];
        if (p < 10){
          int ko = kOff + (p + 2) * 64;
          #pragma unroll
          for (int cf = 0; cf < 4; ++cf)
            Bv[cf][sl] = *(const short8*)(bp[cf] + (ko ^ xr4[cf]));
        }
        acc[0][0] = MFMA(A0[p], b0v, acc[0][0], 0, 0, 0);
        acc[0][1] = MFMA(A0[p], b1v, acc[0][1], 0, 0, 0);
        acc[0][2] = MFMA(A0[p], b2v, acc[0][2], 0, 0, 0);
        acc[0][3] = MFMA(A0[p], b3v, acc[0][3], 0, 0, 0);
        acc[1][0] = MFMA(A1[p], b0v, acc[1][0], 0, 0, 0);
        acc[1][1] = MFMA(A1[p], b1v, acc[1][1], 0, 0, 0);
        acc[1][2] = MFMA(A1[p], b2v, acc[1][2], 0, 0, 0);
        acc[1][3] = MFMA(A1[p], b3v, acc[1][3], 0, 0, 0);
      }
    }

    // ===== two-pass kgg merge into Gt[128][68] =====
    {
      int r0 = rg * 32 + (lane >> 4) * 4;
      if (kgg == 0){
        #pragma unroll
        for (int rf = 0; rf < 2; ++rf)
          #pragma unroll
          for (int cf = 0; cf < 4; ++cf)
            #pragma unroll
            for (int r = 0; r < 4; ++r)
              Gt[(r0 + rf * 16 + r) * 68 + cf * 16 + cb] = acc[rf][cf][r];
      }
      __syncthreads();
      if (kgg == 1){
        #pragma unroll
        for (int rf = 0; rf < 2; ++rf)
          #pragma unroll
          for (int cf = 0; cf < 4; ++cf)
            #pragma unroll
            for (int r = 0; r < 4; ++r)
              Gt[(r0 + rf * 16 + r) * 68 + cf * 16 + cb] += acc[rf][cf][r];
      }
      __syncthreads();
    }

    // ===== pairwise partial exchange (send other row-half, f32, dbuf t&1) =====
    {
      int r  = tid >> 3;
      int c8 = (tid & 7) * 8;
      const unsigned long long* s64 =
          (const unsigned long long*)&Gt[((1 - kg) * 64 + r) * 68 + c8];
      unsigned long long* dst =
          (unsigned long long*)(pbuf + (((size_t)(t & 1) * 256 + bx) * 4096) + r * 64 + c8);
      #pragma unroll
      for (int j = 0; j < 4; ++j)
        __hip_atomic_store(dst + j, s64[j], __ATOMIC_RELAXED, __HIP_MEMORY_SCOPE_AGENT);
    }
    __syncthreads();   // drain pbuf stores (all waves)
    if (tid == 0){
      __hip_atomic_store(&pflags[bx], (unsigned)(t + 1), __ATOMIC_RELAXED, __HIP_MEMORY_SCOPE_AGENT);
      while (__hip_atomic_load(&pflags[bx ^ 1], __ATOMIC_RELAXED, __HIP_MEMORY_SCOPE_AGENT) < (unsigned)(t + 1))
        __builtin_amdgcn_s_sleep(1);
    }
    __syncthreads();
    {
      int r  = tid >> 3;
      int c8 = (tid & 7) * 8;
      const unsigned long long* src =
          (const unsigned long long*)(pbuf + (((size_t)(t & 1) * 256 + (bx ^ 1)) * 4096) + r * 64 + c8);
      float* gd = &Gt[(kg * 64 + r) * 68 + c8];
      #pragma unroll
      for (int j = 0; j < 4; ++j){
        unsigned long long v = __hip_atomic_load(src + j, __ATOMIC_RELAXED, __HIP_MEMORY_SCOPE_AGENT);
        union { unsigned long long q; float f[2]; } uu; uu.q = v;
        gd[2 * j]     += uu.f[0];
        gd[2 * j + 1] += uu.f[1];
      }
    }
    __syncthreads();

    // ===== elementwise on own row-half: 1 row x 2 units per thread =====
    {
      const float* gr = &Gt[erl * 68];
      float gi0 = gr[     eup] + Bls[     eup];
      float gf0 = gr[16 + eup] + Bls[16 + eup];
      float gg0 = gr[32 + eup] + Bls[32 + eup];
      float go0 = gr[48 + eup] + Bls[48 + eup];
      float gi1 = gr[     eup + 1] + Bls[     eup + 1];
      float gf1 = gr[16 + eup + 1] + Bls[16 + eup + 1];
      float gg1 = gr[32 + eup + 1] + Bls[32 + eup + 1];
      float go1 = gr[48 + eup + 1] + Bls[48 + eup + 1];

      float iv0 = 1.f / (1.f + __expf(-gi0));
      float fv0 = 1.f / (1.f + __expf(-gf0));
      float e20 = __expf(-2.f * fmaxf(fminf(gg0, 30.f), -30.f));
      float gv0 = (1.f - e20) / (1.f + e20);
      float ov0 = 1.f / (1.f + __expf(-go0));
      float cn0 = cst0 * fv0 + iv0 * gv0;
      cst0 = cn0;
      float ec0 = __expf(-2.f * fmaxf(fminf(cn0, 30.f), -30.f));
      float hv0 = ov0 * (1.f - ec0) / (1.f + ec0);

      float iv1 = 1.f / (1.f + __expf(-gi1));
      float fv1 = 1.f / (1.f + __expf(-gf1));
      float e21 = __expf(-2.f * fmaxf(fminf(gg1, 30.f), -30.f));
      float gv1 = (1.f - e21) / (1.f + e21);
      float ov1 = 1.f / (1.f + __expf(-go1));
      float cn1 = cst1 * fv1 + iv1 * gv1;
      cst1 = cn1;
      float ec1 = __expf(-2.f * fmaxf(fminf(cn1, 30.f), -30.f));
      float hv1 = ov1 * (1.f - ec1) / (1.f + ec1);

      __hip_atomic_store((unsigned int*)(hout + (size_t)(b0 + erl) * HSZ + u0 + eup),
                         pack2(hv0, hv1), __ATOMIC_RELAXED, __HIP_MEMORY_SCOPE_AGENT);
    }
    __syncthreads();   // drain h-stores before flag

    // ===== arrive: monotonic h flag =====
    if (tid == 0)
      __hip_atomic_store(&hflags[bx], (unsigned)(t + 1), __ATOMIC_RELAXED, __HIP_MEMORY_SCOPE_AGENT);
  }
}

// ---------------- final FC: out[256][1000] = h @ Wfc^T + b ----------------
__global__ __launch_bounds__(256, 1)
void fc_kernel(const unsigned short* __restrict__ h, const unsigned short* __restrict__ wfc,
               const float* __restrict__ bfc, float* __restrict__ out){
  int bx = blockIdx.x, tid = threadIdx.x;
  int wave = tid >> 6, lane = tid & 63;
  int row0 = (bx >> 4) * 64 + wave * 16;
  int col0 = (bx & 15) * 64;
  int lr = lane & 15, lk = (lane >> 4) * 8;
  floatx4 acc[4] = {{0.f,0.f,0.f,0.f},{0.f,0.f,0.f,0.f},{0.f,0.f,0.f,0.f},{0.f,0.f,0.f,0.f}};
  #pragma unroll 4
  for (int ks = 0; ks < 32; ++ks){
    int k = ks * 32 + lk;
    short8 a = *(const short8*)(h + (size_t)(row0 + lr) * 1024 + k);
    #pragma unroll
    for (int fj = 0; fj < 4; ++fj){
      short8 b = *(const short8*)(wfc + (size_t)(col0 + fj * 16 + lr) * 1024 + k);
      acc[fj] = MFMA(a, b, acc[fj], 0, 0, 0);
    }
  }
  #pragma unroll
  for (int fj = 0; fj < 4; ++fj){
    int col = col0 + fj * 16 + lr;
    if (col < 1000){
      #pragma unroll
      for (int r = 0; r < 4; ++r){
        int row = row0 + (lane >> 4) * 4 + r;
        out[(size_t)row * 1000 + col] = acc[fj][r] + bfc[col];
      }
    }
  }
}

// ---------------- launch ----------------
extern "C" void kernel_launch(void* const* d_in, const int* in_sizes, int n_in,
                              void* d_out, int out_size, void* d_ws, size_t ws_size,
                              hipStream_t stream){
  const float* x    = (const float*)d_in[0];
  const float* wx2h = (const float*)d_in[1];
  const float* bx2h = (const float*)d_in[2];
  const float* wh2h = (const float*)d_in[3];
  const float* bh2h = (const float*)d_in[4];
  const float* wfc  = (const float*)d_in[5];
  const float* bfc  = (const float*)d_in[6];
  float* out = (float*)d_out;
  char* ws = (char*)d_ws;

  // ws layout (bytes)
  unsigned short* Wcat   = (unsigned short*)(ws + 0);            //  12,582,912
  unsigned short* Wfcb   = (unsigned short*)(ws + 12582912);     //   2,097,152
  float*          bias   = (float*)         (ws + 14680064);     //      16,384
  unsigned short* xbf    = (unsigned short*)(ws + 14696448);     //  67,108,864
  unsigned short* hseq   = (unsigned short*)(ws + 81805312);     // 134,742,016 (257 x 512KB)
  float*          pbuf   = (float*)         (ws + 216547328);    //   8,388,608 (2x256x16KB)
  unsigned int*   hflags = (unsigned int*)  (ws + 224935936);    //       1,024
  unsigned int*   pflags = (unsigned int*)  (ws + 224936960);    //       1,024
  // total ~225 MB

  (void)hipFuncSetAttribute((const void*)lstm_persist,
                            hipFuncAttributeMaxDynamicSharedMemorySize, 133632);

  hipLaunchKernelGGL(prep_wcat, dim3(3072), dim3(256), 0, stream, wx2h, wh2h, bx2h, bh2h, Wcat, bias);
  hipLaunchKernelGGL(prep_wfc,  dim3(512),  dim3(256), 0, stream, wfc, Wfcb);
  hipLaunchKernelGGL(prep_x,    dim3(16384),dim3(256), 0, stream, x, xbf);
  hipLaunchKernelGGL(init_misc, dim3(512),  dim3(256), 0, stream,
                     (unsigned int*)hseq, hflags, 512);

  hipLaunchKernelGGL(lstm_persist, dim3(256), dim3(512), 133632, stream,
                     xbf, Wcat, bias, hseq, pbuf, hflags, pflags);

  // final h = hseq[256]
  hipLaunchKernelGGL(fc_kernel, dim3(64), dim3(256), 0, stream,
                     hseq + (size_t)256 * BQ * HSZ, Wfcb, bfc, out);
}